// Round 33
// baseline (87.743 us; speedup 1.0000x reference)
//
#include <hip/hip_runtime.h>

#define T_STEPS 2000
#define B_DIM 16
#define L_DIM 1024

// FitzHugh-Nagumo Euler — BIT-EXACT match to the XLA-compiled f32 jax ref
// (R30: absmax == 0.0). Pinned arithmetic schedule (flag-proof):
//   v3=(v*v)*v ; t2=c3*v3 ; a1=fma(1.1,v,-t2) ; a2=fma(-dt,s,a1)
//   vn=fma(dt,z,a2) ; u1=v+0.7 ; u3=fma(-0.8,s,u1) ; s'=fma(0.008,u3,s)
//   out=0.5*vn ; row 0 = 0
// R33 perf changes vs R31 (arithmetic untouched):
//  1. PLAIN stores (drop nontemporal): R31/R32 hit a ~50-100cyc/256B store
//     wall — nt-stores bypass L2/L3, so each 256B segment at 4KB stride is
//     its own DRAM row activation. Plain stores let the 16 blocks sharing
//     each 4KB output page merge their segments in cache before writeback.
//  2. XCD-chunked swizzle lb=(h&7)*32+(h>>3): co-paged blocks (0..15 = all
//     of b=0) land on ONE XCD -> segments merge in that XCD's private L2.
__device__ __forceinline__ float vmulf(float a, float b) {
    float d; asm("v_mul_f32 %0, %1, %2" : "=v"(d) : "v"(a), "v"(b)); return d;
}
__device__ __forceinline__ float vaddf(float a, float b) {
    float d; asm("v_add_f32 %0, %1, %2" : "=v"(d) : "v"(a), "v"(b)); return d;
}
__device__ __forceinline__ float vfma(float a, float b, float c) {
    float d; asm("v_fma_f32 %0, %1, %2, %3" : "=v"(d) : "v"(a), "v"(b), "v"(c)); return d;
}
__device__ __forceinline__ float vfma_negc(float a, float b, float c) {   // a*b - c
    float d; asm("v_fma_f32 %0, %1, %2, -%3" : "=v"(d) : "v"(a), "v"(b), "v"(c)); return d;
}
__device__ __forceinline__ float vfma_nega(float a, float b, float c) {   // -a*b + c
    float d; asm("v_fma_f32 %0, -%1, %2, %3" : "=v"(d) : "v"(a), "v"(b), "v"(c)); return d;
}

__global__ __launch_bounds__(64, 1) void fh_kernel(const float* __restrict__ z,
                                                   float* __restrict__ out) {
    const float C_1P = (float)(1.0 + 0.1);   // f32(1.1)
    const float C_3  = (float)(0.1 / 3.0);   // 0.033333335f
    const float C_DT = 0.1f;
    const float C_SK = (float)(0.1 * 0.08);  // 0.008f
    const float C_07 = 0.7f;
    const float C_08 = 0.8f;

    // XCD-chunked bijective swizzle: hw blocks h with h%8==x all map to
    // logical chunk [x*32, x*32+32) -> one XCD owns 32 consecutive logical
    // blocks = two full b-pages worth of chains.
    const int lb = ((blockIdx.x & 7) << 5) | (blockIdx.x >> 3);
    const int idx = lb * 64 + threadIdx.x;   // chain id 0..16383
    const int b = idx >> 10;
    const int l = idx & 1023;
    const size_t base = (size_t)b * T_STEPS * L_DIM + l;
    const float* zp = z + base;
    float* outp = out + base;

    constexpr int STEPS = T_STEPS - 1;        // 1999 updates
    constexpr int D = 64;                     // prefetch ring depth
    constexpr int SAFE = 1920;                // chunks c<1920: pf<=1983<STEPS
    constexpr int TAIL = STEPS - 1984;        // 15

    float v = 0.0f, s = 0.0f;                 // pure f32 carries

    outp[0] = 0.0f;                           // k = 0 row
    outp += L_DIM;

    float ring[D];
#pragma unroll
    for (int i = 0; i < D; ++i)
        ring[i] = zp[(size_t)i * L_DIM];

#define FH_STEP(ZK)                                            \
    do {                                                       \
        const float v3 = vmulf(vmulf(v, v), v);                \
        const float t2 = vmulf(C_3, v3);                       \
        const float a1 = vfma_negc(C_1P, v, t2);               \
        const float a2 = vfma_nega(C_DT, s, a1);               \
        const float vn = vfma(C_DT, (ZK), a2);                 \
        const float u1 = vaddf(v, C_07);                       \
        const float u3 = vfma_nega(C_08, s, u1);               \
        s = vfma(C_SK, u3, s);                                 \
        v = vn;                                                \
        *outp = vmulf(0.5f, v);                                \
        outp += L_DIM;                                         \
    } while (0)

    // main chunks: steps 0..1919, prefetch unclamped (pf = c+D+i <= 1983)
    for (int c = 0; c < SAFE; c += D) {
        const float* zpf = zp + (size_t)(c + D) * L_DIM;
#pragma unroll
        for (int i = 0; i < D; ++i) {
            const float zk = ring[i];
            ring[i] = zpf[(size_t)i * L_DIM];
            FH_STEP(zk);
        }
    }

    // clamped chunk: steps 1920..1983, prefetch pf = 1984+i clamped to 1998
    {
        const float* zpf = zp + (size_t)(SAFE + D) * L_DIM;
#pragma unroll
        for (int i = 0; i < D; ++i) {
            const float zk = ring[i];
            const int io = (i < TAIL) ? i : (TAIL - 1);   // pf <= 1998
            ring[i] = zpf[(size_t)io * L_DIM];
            FH_STEP(zk);
        }
    }

    // tail: steps 1984..1998 (no prefetch)
#pragma unroll
    for (int i = 0; i < TAIL; ++i) {
        const float zk = ring[i];
        FH_STEP(zk);
    }
#undef FH_STEP
}

extern "C" void kernel_launch(void* const* d_in, const int* in_sizes, int n_in,
                              void* d_out, int out_size, void* d_ws, size_t ws_size,
                              hipStream_t stream) {
    const float* z = (const float*)d_in[0];
    float* out = (float*)d_out;
    const int total = B_DIM * L_DIM;          // 16384 independent chains
    dim3 grid(total / 64);                    // 256 blocks -> 1 wave per CU
    dim3 block(64);
    hipLaunchKernelGGL(fh_kernel, grid, block, 0, stream, z, out);
}